// Round 1
// baseline (1170.954 us; speedup 1.0000x reference)
//
#include <hip/hip_runtime.h>
#include <hip/hip_bf16.h>
#include <math.h>

// Gabor transform: out[b,f,t] = sum_l signal[b,l] * exp(-0.5*((l-tc[t])/819.2)^2)
//                                      * cos(2*pi*fv[f]*l/8192)
// B=32, L=8192, F=128, T=128.
// fv[f] = trunc(f * fp32(4096/127)), tc[t] = trunc(t * fp32(8191/127))  (verified
// to match both jnp-fp32 and np-f64 linspace->int32 for all 128 indices).
// cos uses the exact identity cos(2*pi*(fv*l mod 8192)/8192) via an LDS table.

#define B_ 32
#define L_ 8192
#define F_ 128
#define T_ 128

__global__ __launch_bounds__(256) void gabor_bt_kernel(
    const float* __restrict__ signal, float* __restrict__ out) {
  const int bt = blockIdx.x;        // 0 .. B*T-1
  const int b = bt >> 7;            // / 128
  const int t = bt & 127;           // % 128
  const int tid = threadIdx.x;      // 256 threads

  __shared__ float v[L_];           // windowed signal, 32 KB
  __shared__ float ctab[L_];        // cos(2*pi*m/8192), 32 KB

  // time center (trunc toward zero like .astype(int32))
  const float tstep = 8191.0f / 127.0f;
  const float tc = truncf((float)t * tstep);
  const float inv_sw = 1.0f / 819.2f;  // 1/sigma_w
  const float cstep = (float)(2.0 * M_PI / 8192.0);

  const float* srow = signal + (size_t)b * L_;
  for (int l = tid; l < L_; l += 256) {
    float d = ((float)l - tc) * inv_sw;
    v[l] = srow[l] * expf(-0.5f * d * d);
    ctab[l] = cosf((float)l * cstep);
  }
  __syncthreads();

  const int lane = tid & 63;
  const int wave = tid >> 6;
  const float fstep = 4096.0f / 127.0f;

  for (int f = wave; f < F_; f += 4) {
    const int fv = (int)((float)f * fstep);
    int m = (fv * lane) & (L_ - 1);
    const int dm = (fv << 6) & (L_ - 1);
    float acc = 0.0f;
#pragma unroll 8
    for (int j = 0; j < L_ / 64; ++j) {
      acc += v[lane + (j << 6)] * ctab[m];
      m = (m + dm) & (L_ - 1);
    }
    // 64-lane butterfly reduction
#pragma unroll
    for (int off = 32; off > 0; off >>= 1)
      acc += __shfl_down(acc, off, 64);
    if (lane == 0)
      out[((size_t)b * F_ + f) * T_ + t] = acc;
  }
}

extern "C" void kernel_launch(void* const* d_in, const int* in_sizes, int n_in,
                              void* d_out, int out_size, void* d_ws, size_t ws_size,
                              hipStream_t stream) {
  const float* signal = (const float*)d_in[0];
  float* out = (float*)d_out;
  gabor_bt_kernel<<<dim3(B_ * T_), dim3(256), 0, stream>>>(signal, out);
}

// Round 2
// 91.128 us; speedup vs baseline: 12.8496x; 12.8496x over previous
//
#include <hip/hip_runtime.h>
#include <hip/hip_bf16.h>
#include <math.h>

// out[b,f,t] = sum_l sig[b,l] * win[t,l] * cos(2*pi*fv[f]*l/8192)
// Recast as split-K f16 MFMA GEMM per b:  D[t][f] = win[t][:] . (ctab*sig)[f][:]^T
// B=32, L=8192, F=T=128.  fv/tc linspace->int32 reproduced exactly in fp32 (verified R0).

#define L_ 8192
#define B_ 32
#define SPLITK 8
#define KCHUNK 1024   // L_/SPLITK
#define BK 64

typedef _Float16 half8 __attribute__((ext_vector_type(8)));
typedef float float4v __attribute__((ext_vector_type(4)));

// ---- ws layout ----
// [0,2MB)        win_f16  [128][8192]
// [2MB,4MB)      ctab_f16 [128][8192]
// [4MB,4.5MB)    sig_f16  [32][8192]
// [4.5MB,20.5MB) partial  [8][32][128][128] fp32
#define WS_WIN 0
#define WS_CTAB (2u * 1024u * 1024u)
#define WS_SIG (4u * 1024u * 1024u)
#define WS_PART (4u * 1024u * 1024u + 512u * 1024u)

__global__ __launch_bounds__(256) void gabor_tables_kernel(
    const float* __restrict__ signal, char* __restrict__ ws) {
  _Float16* win = (_Float16*)(ws + WS_WIN);
  _Float16* ctab = (_Float16*)(ws + WS_CTAB);
  _Float16* sigh = (_Float16*)(ws + WS_SIG);
  const int row = blockIdx.x;
  const int tid = threadIdx.x;
  if (row < 128) {  // gaussian window rows (t)
    const float tc = truncf((float)row * (8191.0f / 127.0f));
    const float inv_sw = 1.0f / 819.2f;
    for (int l = tid; l < L_; l += 256) {
      float d = ((float)l - tc) * inv_sw;
      win[row * L_ + l] = (_Float16)__expf(-0.5f * d * d);
    }
  } else if (row < 256) {  // cos rows (f), exact integer phase mod 8192
    const int f = row - 128;
    const int fv = (int)((float)f * (4096.0f / 127.0f));
    const float cstep = (float)(2.0 * M_PI / 8192.0);
    for (int l = tid; l < L_; l += 256) {
      int m = (fv * l) & (L_ - 1);
      ctab[(size_t)f * L_ + l] = (_Float16)__cosf((float)m * cstep);
    }
  } else {  // signal -> f16
    const int b = row - 256;
    for (int l = tid; l < L_; l += 256)
      sigh[b * L_ + l] = (_Float16)signal[b * L_ + l];
  }
}

// 128x128 tile per (b, kc).  4 waves in 2x2 quadrants, 4x4 16x16x32 frags each.
__global__ __launch_bounds__(256) void gabor_gemm_kernel(char* __restrict__ ws) {
  const _Float16* win = (const _Float16*)(ws + WS_WIN);
  const _Float16* ctab = (const _Float16*)(ws + WS_CTAB);
  const _Float16* sigh = (const _Float16*)(ws + WS_SIG);
  float* partial = (float*)(ws + WS_PART);

  const int kc = blockIdx.x & 7;
  const int b = blockIdx.x >> 3;
  const int tid = threadIdx.x;

  __shared__ _Float16 As[128][72];  // win rows (t), +8 pad -> frag reads 2-way only
  __shared__ _Float16 Bs[128][72];  // ctab*sig rows (f)

  const int lane = tid & 63;
  const int wv = tid >> 6;
  const int wm = (wv >> 1) * 64;  // t quadrant
  const int wn = (wv & 1) * 64;   // f quadrant
  const int frow = lane & 15;
  const int kq = (lane >> 4) * 8;

  float4v acc[4][4];
#pragma unroll
  for (int i = 0; i < 4; ++i)
#pragma unroll
    for (int j = 0; j < 4; ++j) acc[i][j] = (float4v)(0.0f);

  const int r0 = tid >> 3;         // 0..31
  const int c8 = (tid & 7) * 8;    // 0..56

  const int l0base = kc * KCHUNK;
  for (int step = 0; step < KCHUNK / BK; ++step) {
    const int l0 = l0base + step * BK;
    __syncthreads();
#pragma unroll
    for (int rep = 0; rep < 4; ++rep) {
      const int row = r0 + rep * 32;
      half8 wvv = *(const half8*)(win + (size_t)row * L_ + l0 + c8);
      half8 cv = *(const half8*)(ctab + (size_t)row * L_ + l0 + c8);
      half8 sv = *(const half8*)(sigh + (size_t)b * L_ + l0 + c8);
      *(half8*)&As[row][c8] = wvv;
      *(half8*)&Bs[row][c8] = cv * sv;
    }
    __syncthreads();
#pragma unroll
    for (int kh = 0; kh < 2; ++kh) {
      const int kk = kh * 32 + kq;
      half8 af[4], bf[4];
#pragma unroll
      for (int i = 0; i < 4; ++i)
        af[i] = *(const half8*)&As[wm + i * 16 + frow][kk];
#pragma unroll
      for (int j = 0; j < 4; ++j)
        bf[j] = *(const half8*)&Bs[wn + j * 16 + frow][kk];
#pragma unroll
      for (int i = 0; i < 4; ++i)
#pragma unroll
        for (int j = 0; j < 4; ++j)
          acc[i][j] = __builtin_amdgcn_mfma_f32_16x16x32_f16(af[i], bf[j],
                                                             acc[i][j], 0, 0, 0);
    }
  }

  // partial[kc][b][f][t], D: col(f)=lane&15, row(t)=(lane>>4)*4+reg
  float* pbase = partial + ((size_t)(kc * B_ + b) << 14);
  const int tq = (lane >> 4) * 4;
#pragma unroll
  for (int i = 0; i < 4; ++i) {
    const int t = wm + i * 16 + tq;
#pragma unroll
    for (int j = 0; j < 4; ++j) {
      const int f = wn + j * 16 + frow;
      *(float4v*)(pbase + f * 128 + t) = acc[i][j];
    }
  }
}

__global__ __launch_bounds__(256) void gabor_reduce_kernel(
    const char* __restrict__ ws, float* __restrict__ out) {
  const float* partial = (const float*)(ws + WS_PART);
  const size_t gi = ((size_t)blockIdx.x * 256 + threadIdx.x) * 4;  // < 524288
  float4v s = (float4v)(0.0f);
#pragma unroll
  for (int kc = 0; kc < SPLITK; ++kc)
    s += *(const float4v*)(partial + (size_t)kc * 524288 + gi);
  *(float4v*)(out + gi) = s;
}

extern "C" void kernel_launch(void* const* d_in, const int* in_sizes, int n_in,
                              void* d_out, int out_size, void* d_ws, size_t ws_size,
                              hipStream_t stream) {
  const float* signal = (const float*)d_in[0];
  float* out = (float*)d_out;
  char* ws = (char*)d_ws;
  gabor_tables_kernel<<<dim3(288), dim3(256), 0, stream>>>(signal, ws);
  gabor_gemm_kernel<<<dim3(B_ * SPLITK), dim3(256), 0, stream>>>(ws);
  gabor_reduce_kernel<<<dim3(512), dim3(256), 0, stream>>>(ws, out);
}

// Round 3
// 88.950 us; speedup vs baseline: 13.1641x; 1.0245x over previous
//
#include <hip/hip_runtime.h>
#include <hip/hip_bf16.h>
#include <math.h>

// out[b,f,t] = sum_l sig[b,l] * win[t,l] * cos(2*pi*fv[f]*l/8192)
// Split-K f16 MFMA GEMM: D[t][f] = win[t][:] . (ctab*sig)[f][:]^T per b.
// B=32, L=8192, F=T=128.  fv/tc = linspace->int32 reproduced exactly (R0).
// R3: splitk 16 (2 blk/CU), LDS double-buffer, A staged via global_load_lds
// from a blocked+XOR-swizzled win table (conflict-free b128 frag reads).

#define L_ 8192
#define B_ 32
#define SPLITK 16
#define KCHUNK 512   // L_/SPLITK
#define BK 64
#define STEPS 8      // KCHUNK/BK

typedef _Float16 half8 __attribute__((ext_vector_type(8)));
typedef float float4v __attribute__((ext_vector_type(4)));

// ws layout:
// [0,2MB)    win_blk [128 kblk][128 t][8 chunks(^t&7)][8 f16]
// [2MB,4MB)  ctab    [128 f][8192] f16
// [4MB,4.5M) sig_f16 [32][8192]
// [4.5M,36.5M) partial [16][32][128 f][128 t] fp32
#define WS_WIN 0
#define WS_CTAB (2u * 1024u * 1024u)
#define WS_SIG (4u * 1024u * 1024u)
#define WS_PART (4u * 1024u * 1024u + 512u * 1024u)

#define GLD_LDS16(gsrc, ldst)                                              \
  __builtin_amdgcn_global_load_lds(                                        \
      (const __attribute__((address_space(1))) void*)(gsrc),               \
      (__attribute__((address_space(3))) void*)(ldst), 16, 0, 0)

__global__ __launch_bounds__(256) void gabor_tables_kernel(
    const float* __restrict__ signal, char* __restrict__ ws) {
  _Float16* win_blk = (_Float16*)(ws + WS_WIN);
  _Float16* ctab = (_Float16*)(ws + WS_CTAB);
  _Float16* sigh = (_Float16*)(ws + WS_SIG);
  const int row = blockIdx.x;
  const int tid = threadIdx.x;
  if (row < 128) {  // gaussian window row t -> blocked + swizzled
    const int t = row;
    const float tc = truncf((float)t * (8191.0f / 127.0f));
    const float inv_sw = 1.0f / 819.2f;
    for (int l = tid; l < L_; l += 256) {
      float d = ((float)l - tc) * inv_sw;
      int kblk = l >> 6, c = (l >> 3) & 7, e = l & 7;
      win_blk[(((kblk << 7) + t) << 6) + (((c ^ (t & 7)) << 3) + e)] =
          (_Float16)__expf(-0.5f * d * d);
    }
  } else if (row < 256) {  // cos row f, exact integer phase mod 8192
    const int f = row - 128;
    const int fv = (int)((float)f * (4096.0f / 127.0f));
    const float cstep = (float)(2.0 * M_PI / 8192.0);
    for (int l = tid; l < L_; l += 256) {
      int m = (fv * l) & (L_ - 1);
      ctab[(size_t)f * L_ + l] = (_Float16)__cosf((float)m * cstep);
    }
  } else {  // signal -> f16
    const int b = row - 256;
    for (int l = tid; l < L_; l += 256)
      sigh[b * L_ + l] = (_Float16)signal[b * L_ + l];
  }
}

__global__ __launch_bounds__(256, 2) void gabor_gemm_kernel(char* __restrict__ ws) {
  const _Float16* win_blk = (const _Float16*)(ws + WS_WIN);
  const _Float16* ctab = (const _Float16*)(ws + WS_CTAB);
  const _Float16* sigh = (const _Float16*)(ws + WS_SIG);
  float* partial = (float*)(ws + WS_PART);

  const int kc = blockIdx.x & (SPLITK - 1);
  const int b = blockIdx.x >> 4;
  const int tid = threadIdx.x;

  __shared__ _Float16 As[2][128 * 64];  // 16 KB each, swizzled rows of 64
  __shared__ _Float16 Bs[2][128][72];   // 18 KB each, +8 pad

  const int lane = tid & 63;
  const int wv = tid >> 6;
  const int wm = (wv >> 1) * 64;  // t quadrant
  const int wn = (wv & 1) * 64;   // f quadrant
  const int frow = lane & 15;
  const int quad = lane >> 4;

  const int r0 = tid >> 3;       // 0..31 (Bs staging row base)
  const int c8 = (tid & 7) * 8;  // 0..56

  float4v acc[4][4];
#pragma unroll
  for (int i = 0; i < 4; ++i)
#pragma unroll
    for (int j = 0; j < 4; ++j) acc[i][j] = (float4v)(0.0f);

  half8 cv[4], sv;

  // --- staging helpers (inlined by compiler) ---
  // A: pure DMA copy of 16KB block kblk into As[buf]
#define STAGE_A(s, buf)                                                     \
  {                                                                         \
    const _Float16* asrc = win_blk + (((size_t)(kc * STEPS + (s)) << 13));  \
    _Float16* adst = &As[buf][0];                                           \
    GLD_LDS16(asrc + tid * 8, adst + tid * 8);                              \
    GLD_LDS16(asrc + 2048 + tid * 8, adst + 2048 + tid * 8);                \
    GLD_LDS16(asrc + 4096 + tid * 8, adst + 4096 + tid * 8);                \
    GLD_LDS16(asrc + 6144 + tid * 8, adst + 6144 + tid * 8);                \
  }
#define LOAD_B(s)                                                           \
  {                                                                         \
    const int l0 = kc * KCHUNK + (s)*BK;                                    \
    sv = *(const half8*)(sigh + (size_t)b * L_ + l0 + c8);                  \
    _Pragma("unroll") for (int rep = 0; rep < 4; ++rep) cv[rep] =           \
        *(const half8*)(ctab + (size_t)(r0 + rep * 32) * L_ + l0 + c8);     \
  }
#define WRITE_B(buf)                                                        \
  {                                                                         \
    _Pragma("unroll") for (int rep = 0; rep < 4; ++rep)                     \
        *(half8*)&Bs[buf][r0 + rep * 32][c8] = cv[rep] * sv;                \
  }

  STAGE_A(0, 0);
  LOAD_B(0);
  WRITE_B(0);

  for (int s = 0; s < STEPS; ++s) {
    const int cb = s & 1, nb = cb ^ 1;
    __syncthreads();  // buf cb ready (drains DMA + Bs writes)
    if (s + 1 < STEPS) {
      STAGE_A(s + 1, nb);
      LOAD_B(s + 1);
    }
#pragma unroll
    for (int kh = 0; kh < 2; ++kh) {
      half8 af[4], bf[4];
      const int chunk = kh * 4 + quad;
#pragma unroll
      for (int i = 0; i < 4; ++i) {
        const int r = wm + i * 16 + frow;
        af[i] = *(const half8*)&As[cb][(r << 6) + ((chunk ^ (r & 7)) << 3)];
      }
#pragma unroll
      for (int j = 0; j < 4; ++j)
        bf[j] = *(const half8*)&Bs[cb][wn + j * 16 + frow][kh * 32 + quad * 8];
#pragma unroll
      for (int i = 0; i < 4; ++i)
#pragma unroll
        for (int j = 0; j < 4; ++j)
          acc[i][j] = __builtin_amdgcn_mfma_f32_16x16x32_f16(af[i], bf[j],
                                                             acc[i][j], 0, 0, 0);
    }
    if (s + 1 < STEPS) WRITE_B(nb);
  }

  // partial[kc][b][f][t]; D frag: col(f)=lane&15, row(t)=(lane>>4)*4+reg
  float* pbase = partial + ((size_t)(kc * B_ + b) << 14);
  const int tq = quad * 4;
#pragma unroll
  for (int i = 0; i < 4; ++i) {
    const int t = wm + i * 16 + tq;
#pragma unroll
    for (int j = 0; j < 4; ++j) {
      const int f = wn + j * 16 + frow;
      *(float4v*)(pbase + f * 128 + t) = acc[i][j];
    }
  }
}

__global__ __launch_bounds__(256) void gabor_reduce_kernel(
    const char* __restrict__ ws, float* __restrict__ out) {
  const float* partial = (const float*)(ws + WS_PART);
  const size_t gi = ((size_t)blockIdx.x * 256 + threadIdx.x) * 4;  // < 524288
  float4v s = (float4v)(0.0f);
#pragma unroll
  for (int kc = 0; kc < SPLITK; ++kc)
    s += *(const float4v*)(partial + (size_t)kc * 524288 + gi);
  *(float4v*)(out + gi) = s;
}

extern "C" void kernel_launch(void* const* d_in, const int* in_sizes, int n_in,
                              void* d_out, int out_size, void* d_ws, size_t ws_size,
                              hipStream_t stream) {
  const float* signal = (const float*)d_in[0];
  float* out = (float*)d_out;
  char* ws = (char*)d_ws;
  gabor_tables_kernel<<<dim3(288), dim3(256), 0, stream>>>(signal, ws);
  gabor_gemm_kernel<<<dim3(B_ * SPLITK), dim3(256), 0, stream>>>(ws);
  gabor_reduce_kernel<<<dim3(512), dim3(256), 0, stream>>>(ws, out);
}